// Round 1
// baseline (267.472 us; speedup 1.0000x reference)
//
#include <hip/hip_runtime.h>
#include <hip/hip_bf16.h>

#define NOPT    5
#define NBATCH  100000
#define MTOT    (NOPT * NBATCH)   // 500000 rows
#define KDIM    600
#define BM      64                // rows per block
#define NKS     19                // k-steps of 32 (last overlaps: k=568..599)
#define NT      5                 // n-tiles of 16 (75 -> 80, tail zero-padded)

typedef __bf16 bf16x8 __attribute__((ext_vector_type(8)));
typedef float  f32x4  __attribute__((ext_vector_type(4)));

__device__ __forceinline__ int kstart(int s) { return (s < 18) ? (s << 5) : 568; }

// Pre-transform W1 [75][600] fp32 -> bf16 image in exact MFMA B-fragment order:
// img[(s*5+t)*512 + l*8 + j] = W1[n=t*16+(l&15)][k=kstart(s)+(l>>4)*8+j], zeros for
// n>=75 and for the duplicated k range of the overlapping tail tile (s==18, kg==0).
__global__ void prep_w1(const float* __restrict__ W1, __bf16* __restrict__ img) {
    const int s  = blockIdx.x / NT;
    const int t  = blockIdx.x % NT;
    const int l  = threadIdx.x;            // 0..63
    const int kg = l >> 4;
    const int n  = t * 16 + (l & 15);
    const int ks = kstart(s);
    bf16x8 v;
#pragma unroll
    for (int j = 0; j < 8; ++j) {
        const int k = ks + kg * 8 + j;
        float f = 0.0f;
        if (n < 75 && !(s == 18 && kg == 0)) f = W1[n * KDIM + k];
        v[j] = (__bf16)f;
    }
    *(bf16x8*)(img + ((size_t)blockIdx.x * 64 + l) * 8) = v;
}

__global__ void __launch_bounds__(256) ans_sel_kernel(
    const float* __restrict__ A,     // [500000][600] fp32 (options-major)
    const float* __restrict__ b1,    // [75]
    const float* __restrict__ W2,    // [75]
    const float* __restrict__ b2,    // [1]
    const __bf16* __restrict__ img,  // prepped W1 fragments
    float* __restrict__ out)         // [100000][5]
{
    __shared__ float  As[2][2048];   // [2][64 rows][32 k] fp32, chunk-XOR-swizzled
    __shared__ __bf16 Bs[2][2560];   // [2][5 tiles][64 lanes][8 bf16] fragment order

    const int tid  = threadIdx.x;
    const int w    = tid >> 6;       // wave 0..3
    const int l    = tid & 63;
    const int kg   = l >> 4;
    const int ln16 = l & 15;
    const int row0 = blockIdx.x * BM;

    f32x4 acc[NT];
#pragma unroll
    for (int t = 0; t < NT; ++t) acc[t] = (f32x4){0.f, 0.f, 0.f, 0.f};

    // staging geometry: each wave DMA's 2x1024B of A (rows w*16..w*16+15) and
    // 1-2x1024B of B. LDS dest is wave-uniform base + lane*16 (linear); the
    // XOR swizzle is applied to the GLOBAL source address (rule #21 / m173).
    const int a_r0 = w * 16 + (l >> 3);   // rows for part 2w   (0..7 within half-tile)
    const int a_r1 = a_r0 + 8;            // rows for part 2w+1
    const int pch  = l & 7;               // physical 16B chunk within the row

    auto stage = [&](int buf, int s) {
        const int k0 = kstart(s);
        {   // A half-tile 0 of this wave
            const int c   = pch ^ (a_r0 & 7);               // logical k-chunk
            int gr = row0 + a_r0; if (gr >= MTOT) gr = MTOT - 1;
            __builtin_amdgcn_global_load_lds(
                (const __attribute__((address_space(1))) void*)(A + (size_t)gr * KDIM + k0 + c * 4),
                (__attribute__((address_space(3))) void*)(&As[buf][(w * 2) * 256]),
                16, 0, 0);
        }
        {   // A half-tile 1
            const int c   = pch ^ (a_r1 & 7);
            int gr = row0 + a_r1; if (gr >= MTOT) gr = MTOT - 1;
            __builtin_amdgcn_global_load_lds(
                (const __attribute__((address_space(1))) void*)(A + (size_t)gr * KDIM + k0 + c * 4),
                (__attribute__((address_space(3))) void*)(&As[buf][(w * 2 + 1) * 256]),
                16, 0, 0);
        }
        // B: 5 linear 1024B parts (wave 0 takes parts 0 and 4)
        for (int i = w; i < NT; i += 4) {
            __builtin_amdgcn_global_load_lds(
                (const __attribute__((address_space(1))) void*)(img + (size_t)s * 2560 + i * 512 + l * 8),
                (__attribute__((address_space(3))) void*)(&Bs[buf][i * 512]),
                16, 0, 0);
        }
    };

    auto compute = [&](int buf) {
        const int r  = w * 16 + ln16;                 // A tile row for this lane
        const f32x4* af = (const f32x4*)As[buf];
        const int c0 = kg * 2;                        // logical k-chunks c0, c0+1
        f32x4 fa0 = af[r * 8 + ((c0    ) ^ (r & 7))];
        f32x4 fa1 = af[r * 8 + ((c0 + 1) ^ (r & 7))];
        bf16x8 a;
        a[0] = (__bf16)fa0[0]; a[1] = (__bf16)fa0[1];
        a[2] = (__bf16)fa0[2]; a[3] = (__bf16)fa0[3];
        a[4] = (__bf16)fa1[0]; a[5] = (__bf16)fa1[1];
        a[6] = (__bf16)fa1[2]; a[7] = (__bf16)fa1[3];
#pragma unroll
        for (int t = 0; t < NT; ++t) {
            bf16x8 b = *(const bf16x8*)(&Bs[buf][t * 512 + l * 8]);
            acc[t] = __builtin_amdgcn_mfma_f32_16x16x32_bf16(a, b, acc[t], 0, 0, 0);
        }
    };

    // 2-phase pipeline: issue next-tile DMA, compute current, one barrier per step
    stage(0, 0);
    __syncthreads();
    int cur = 0;
    for (int s = 0; s < NKS - 1; ++s) {
        stage(cur ^ 1, s + 1);
        compute(cur);
        __syncthreads();
        cur ^= 1;
    }
    compute(cur);

    // Epilogue: C[row=(kg*4+q)][n=t*16+ln16] per lane (verified m89/m91 layout).
    // bias + relu + dot(W2) per lane, then butterfly-sum over the 16-lane n-group.
    float sq[4] = {0.f, 0.f, 0.f, 0.f};
#pragma unroll
    for (int t = 0; t < NT; ++t) {
        const int n = t * 16 + ln16;
        const float b1v = (n < 75) ? b1[n] : 0.f;
        const float w2v = (n < 75) ? W2[n] : 0.f;
#pragma unroll
        for (int q = 0; q < 4; ++q) {
            float h = acc[t][q] + b1v;
            h = h > 0.f ? h : 0.f;
            sq[q] += h * w2v;
        }
    }
#pragma unroll
    for (int m = 1; m < 16; m <<= 1) {
#pragma unroll
        for (int q = 0; q < 4; ++q) sq[q] += __shfl_xor(sq[q], m, 64);
    }
    if (ln16 == 0) {
        const float bb = b2[0];
#pragma unroll
        for (int q = 0; q < 4; ++q) {
            const int R = row0 + w * 16 + kg * 4 + q;   // global row = o*NBATCH + b
            if (R < MTOT) {
                const int o = R / NBATCH;
                const int b = R % NBATCH;
                out[(size_t)b * NOPT + o] = sq[q] + bb;
            }
        }
    }
}

extern "C" void kernel_launch(void* const* d_in, const int* in_sizes, int n_in,
                              void* d_out, int out_size, void* d_ws, size_t ws_size,
                              hipStream_t stream) {
    const float* A  = (const float*)d_in[0];
    const float* W1 = (const float*)d_in[1];
    const float* b1 = (const float*)d_in[2];
    const float* W2 = (const float*)d_in[3];
    const float* b2 = (const float*)d_in[4];
    float* out = (float*)d_out;
    __bf16* img = (__bf16*)d_ws;     // needs 19*5*64*8*2 = 97280 B

    prep_w1<<<NKS * NT, 64, 0, stream>>>(W1, img);

    const int grid = (MTOT + BM - 1) / BM;   // 7813
    ans_sel_kernel<<<grid, 256, 0, stream>>>(A, b1, W2, b2, img, out);
}